// Round 5
// baseline (191.816 us; speedup 1.0000x reference)
//
#include <hip/hip_runtime.h>

// 2-layer GCN, pull-based aggregation, bf16 gather tables, wide vector gathers.
// Layer1 pull: 16 lanes/row (ushort4), 4 edges per wave-load, xor-reduce.
// Layer2 pull: 8 lanes/row (ushort4), 8 edges per wave-load, xor-reduce.

#define TPB 256
#define NPB 512     // nodes per bucket (dst >> 9)
#define BCAP 8192   // max edges per bucket (mean ~6122)
#define TILE_E 2048 // edges per binning block

__device__ __forceinline__ float bf2f(unsigned short u) {
    unsigned int v = ((unsigned int)u) << 16;
    return __builtin_bit_cast(float, v);
}
__device__ __forceinline__ unsigned short f2bf(float f) {
    unsigned int u = __builtin_bit_cast(unsigned int, f);
    u += 0x7FFFu + ((u >> 16) & 1u);  // round-to-nearest-even
    return (unsigned short)(u >> 16);
}

__device__ __forceinline__ int edge_val(const void* ei, int is64, long long idx) {
    if (is64) return (int)((const long long*)ei)[idx];
    return ((const int*)ei)[idx];
}

// int64 vs int32 edge buffer detect; also zero bucket_wp.
__global__ void k_detect(const unsigned int* __restrict__ w, int nelems, int* flag,
                         int* __restrict__ bucket_wp) {
    __shared__ unsigned int red[TPB];
    bucket_wp[threadIdx.x] = 0;
    unsigned int acc = 0;
    int limit = nelems < 16384 ? nelems : 16384;
    for (int i = 1 + 2 * (int)threadIdx.x; i < limit; i += 2 * TPB) acc |= w[i];
    red[threadIdx.x] = acc;
    __syncthreads();
    for (int s = TPB / 2; s > 0; s >>= 1) {
        if ((int)threadIdx.x < s) red[threadIdx.x] |= red[threadIdx.x + s];
        __syncthreads();
    }
    if (threadIdx.x == 0) *flag = (red[0] == 0u) ? 1 : 0;
}

// Pass A: bin edges by bucket = dst>>9 into gstage (bucket-major, BCAP stride).
__launch_bounds__(TPB)
__global__ void k_binA(const void* __restrict__ ei, const int* __restrict__ flag, int E,
                       int nb, unsigned int* __restrict__ gstage, int* __restrict__ bucket_wp) {
    __shared__ int lcnt[256];
    __shared__ int lboff[256];
    __shared__ int lrank[256];
    __shared__ int gbase[256];
    __shared__ int sh[256];
    __shared__ unsigned int spair[TILE_E];
    __shared__ unsigned char sbuck[TILE_E];
    int is64 = *flag;
    int t = threadIdx.x;
    int base_e = blockIdx.x * TILE_E;
    int ne = E - base_e;
    if (ne > TILE_E) ne = TILE_E;

    lcnt[t] = 0;
    lrank[t] = 0;
    __syncthreads();

    int myb[8];
    unsigned int mypair[8];
#pragma unroll
    for (int k = 0; k < 8; ++k) {
        int idx = t + k * TPB;
        myb[k] = -1;
        if (idx < ne) {
            long long e = base_e + idx;
            int s = edge_val(ei, is64, e);
            int d = edge_val(ei, is64, (long long)E + e);
            int b = d >> 9;
            myb[k] = b;
            mypair[k] = (unsigned int)s | ((unsigned int)(d & (NPB - 1)) << 20);
            atomicAdd(&lcnt[b], 1);
        }
    }
    __syncthreads();

    int v0 = lcnt[t];
    sh[t] = v0;
    __syncthreads();
    for (int st = 1; st < TPB; st <<= 1) {
        int u = (t >= st) ? sh[t - st] : 0;
        __syncthreads();
        sh[t] += u;
        __syncthreads();
    }
    lboff[t] = sh[t] - v0;
    if (t < nb && v0 > 0) gbase[t] = atomicAdd(&bucket_wp[t], v0);
    __syncthreads();

#pragma unroll
    for (int k = 0; k < 8; ++k) {
        int b = myb[k];
        if (b >= 0) {
            int r = atomicAdd(&lrank[b], 1);
            int slot = lboff[b] + r;
            spair[slot] = mypair[k];
            sbuck[slot] = (unsigned char)b;
        }
    }
    __syncthreads();

    for (int j = t; j < ne; j += TPB) {
        int b = sbuck[j];
        int pos = gbase[b] + (j - lboff[b]);
        if (pos < BCAP) gstage[(size_t)b * BCAP + pos] = spair[j];
    }
}

__global__ void k_bscan(const int* __restrict__ bucket_wp, int nb, int* __restrict__ bcount,
                        int* __restrict__ bucket_base, int* __restrict__ rowptr, int n_nodes) {
    __shared__ int sh[TPB];
    int t = threadIdx.x;
    int c = (t < nb) ? bucket_wp[t] : 0;
    if (c > BCAP) c = BCAP;
    sh[t] = c;
    __syncthreads();
    for (int st = 1; st < TPB; st <<= 1) {
        int u = (t >= st) ? sh[t - st] : 0;
        __syncthreads();
        sh[t] += u;
        __syncthreads();
    }
    if (t < nb) {
        bcount[t] = c;
        bucket_base[t] = sh[t] - c;
    }
    if (t == TPB - 1) rowptr[n_nodes] = sh[t];
}

// Pass B: per bucket, build CSR segment in LDS; coalesced csr/cnt/rowptr writes.
__launch_bounds__(512)
__global__ void k_csrB(const unsigned int* __restrict__ gstage, const int* __restrict__ bcount,
                       const int* __restrict__ bucket_base, int* __restrict__ csr,
                       int* __restrict__ cnt, int* __restrict__ rowptr, int n_nodes) {
    __shared__ int lcnt[NPB];
    __shared__ int lptr[NPB];
    __shared__ int lrank[NPB];
    __shared__ int sh[NPB];
    __shared__ int lsrc[BCAP];
    int b = blockIdx.x;
    int t = threadIdx.x;
    int cb = bcount[b];
    const unsigned int* gp = gstage + (size_t)b * BCAP;
    int cbase = bucket_base[b];

    lcnt[t] = 0;
    lrank[t] = 0;
    __syncthreads();
    for (int j = t; j < cb; j += 512) atomicAdd(&lcnt[gp[j] >> 20], 1);
    __syncthreads();
    int v0 = lcnt[t];
    sh[t] = v0;
    __syncthreads();
    for (int st = 1; st < NPB; st <<= 1) {
        int u = (t >= st) ? sh[t - st] : 0;
        __syncthreads();
        sh[t] += u;
        __syncthreads();
    }
    lptr[t] = sh[t] - v0;
    int node = b * NPB + t;
    if (node < n_nodes) {
        rowptr[node] = cbase + lptr[t];
        cnt[node] = v0;
    }
    __syncthreads();
    for (int j = t; j < cb; j += 512) {
        unsigned int w = gp[j];
        int dl = w >> 20;
        int r = atomicAdd(&lrank[dl], 1);
        lsrc[lptr[dl] + r] = (int)(w & 0xFFFFFu);
    }
    __syncthreads();
    for (int j = t; j < cb; j += 512) csr[cbase + j] = lsrc[j];
}

// g1b[n] = bf16((x[n]@W1)*dinv[n]); dinv from cnt+1. 16 nodes/block, float4 staging.
__launch_bounds__(TPB)
__global__ void k_gemm1(const float* __restrict__ x, const float* __restrict__ W1,
                        const int* __restrict__ cnt, float* __restrict__ dinv,
                        unsigned short* __restrict__ g1b, int n_nodes) {
    __shared__ float Ws[64][64];
    __shared__ float Xs[16][64];
    int t = threadIdx.x;
    for (int i = t; i < 1024; i += TPB) ((float4*)Ws)[i] = ((const float4*)W1)[i];
    int node0 = blockIdx.x * 16;
    {
        int nl = t >> 4, c = t & 15;
        int node = node0 + nl;
        float4 v = make_float4(0.f, 0.f, 0.f, 0.f);
        if (node < n_nodes) v = ((const float4*)(x + (size_t)node * 64))[c];
        ((float4*)Xs[nl])[c] = v;
    }
    __syncthreads();
    int f = t & 63;
#pragma unroll
    for (int it = 0; it < 4; ++it) {
        int nl = (t >> 6) + 4 * it;
        int node = node0 + nl;
        if (node >= n_nodes) continue;
        float acc = 0.f;
#pragma unroll
        for (int k = 0; k < 64; ++k) acc += Xs[nl][k] * Ws[k][f];
        float di = rsqrtf((float)(cnt[node] + 1));
        g1b[(size_t)node * 64 + f] = f2bf(acc * di);
        if (f == 0) dinv[node] = di;
    }
}

// Fused layer1 pull + layer2 GEMM. 1 wave/node, 4 nodes/block.
// Lane layout: q = lane>>4 (edge slot 0..3), fl = lane&15 (feature chunk, 4 feats).
__launch_bounds__(TPB)
__global__ void k_pull1f(const int* __restrict__ rowptr, const int* __restrict__ csr,
                         const unsigned short* __restrict__ g1b, const float* __restrict__ dinv,
                         const float* __restrict__ b1, const float* __restrict__ W2,
                         unsigned short* __restrict__ g2b, int n_nodes) {
    __shared__ float Ws[64][32];
    __shared__ float Hs[4][64];
    __shared__ float dins[4];
    int t = threadIdx.x;
    for (int i = t; i < 64 * 32; i += TPB) Ws[i >> 5][i & 31] = W2[i];
    int node0 = blockIdx.x * 4;
    int w = t >> 6, lane = t & 63;
    int q = lane >> 4, fl = lane & 15;
    int node = node0 + w;
    if (node < n_nodes) {
        int base = rowptr[node], cntv = rowptr[node + 1] - base;
        float a0 = 0.f, a1 = 0.f, a2 = 0.f, a3 = 0.f;
        for (int off = 0; off < cntv; off += 8) {
            int e0 = off + q, e1 = off + 4 + q;
            bool p0 = e0 < cntv, p1 = e1 < cntv;
            ushort4 u0, u1;
            if (p0) {
                int s = csr[base + e0];
                u0 = ((const ushort4*)(g1b + (size_t)s * 64))[fl];
            }
            if (p1) {
                int s = csr[base + e1];
                u1 = ((const ushort4*)(g1b + (size_t)s * 64))[fl];
            }
            if (p0) {
                a0 += bf2f(u0.x); a1 += bf2f(u0.y); a2 += bf2f(u0.z); a3 += bf2f(u0.w);
            }
            if (p1) {
                a0 += bf2f(u1.x); a1 += bf2f(u1.y); a2 += bf2f(u1.z); a3 += bf2f(u1.w);
            }
        }
        if (q == 0) {  // self-loop row
            ushort4 u = ((const ushort4*)(g1b + (size_t)node * 64))[fl];
            a0 += bf2f(u.x); a1 += bf2f(u.y); a2 += bf2f(u.z); a3 += bf2f(u.w);
        }
        // reduce over edge slots (lanes differing in bits 4,5)
        a0 += __shfl_xor(a0, 16); a1 += __shfl_xor(a1, 16);
        a2 += __shfl_xor(a2, 16); a3 += __shfl_xor(a3, 16);
        a0 += __shfl_xor(a0, 32); a1 += __shfl_xor(a1, 32);
        a2 += __shfl_xor(a2, 32); a3 += __shfl_xor(a3, 32);
        float di = dinv[node];
        if (q == 0) {
            int f0 = fl * 4;
            float4 h;
            h.x = di * a0 + b1[f0 + 0];
            h.y = di * a1 + b1[f0 + 1];
            h.z = di * a2 + b1[f0 + 2];
            h.w = di * a3 + b1[f0 + 3];
            ((float4*)Hs[w])[fl] = h;
            if (fl == 0) dins[w] = di;
        }
    } else if (lane < 16) {
        ((float4*)Hs[w])[lane] = make_float4(0.f, 0.f, 0.f, 0.f);
    }
    __syncthreads();
    if (t < 128) {
        int nl = t >> 5, f = t & 31;
        int n2 = node0 + nl;
        if (n2 < n_nodes) {
            float acc = 0.f;
#pragma unroll
            for (int k = 0; k < 64; ++k) acc += Hs[nl][k] * Ws[k][f];
            g2b[(size_t)n2 * 32 + f] = f2bf(acc * dins[nl]);
        }
    }
}

// Layer2 pull. 1 wave/node. q = lane>>3 (edge slot 0..7), fl = lane&7 (4 feats).
__global__ void k_pull2(const int* __restrict__ rowptr, const int* __restrict__ csr,
                        const unsigned short* __restrict__ g2b, const float* __restrict__ dinv,
                        const float* __restrict__ b2, float* __restrict__ out, int n_nodes) {
    int node = blockIdx.x * 4 + (threadIdx.x >> 6);
    int lane = threadIdx.x & 63;
    int q = lane >> 3, fl = lane & 7;
    if (node >= n_nodes) return;
    int base = rowptr[node], cntv = rowptr[node + 1] - base;
    float a0 = 0.f, a1 = 0.f, a2 = 0.f, a3 = 0.f;
    for (int off = 0; off < cntv; off += 16) {
        int e0 = off + q, e1 = off + 8 + q;
        bool p0 = e0 < cntv, p1 = e1 < cntv;
        ushort4 u0, u1;
        if (p0) {
            int s = csr[base + e0];
            u0 = ((const ushort4*)(g2b + (size_t)s * 32))[fl];
        }
        if (p1) {
            int s = csr[base + e1];
            u1 = ((const ushort4*)(g2b + (size_t)s * 32))[fl];
        }
        if (p0) {
            a0 += bf2f(u0.x); a1 += bf2f(u0.y); a2 += bf2f(u0.z); a3 += bf2f(u0.w);
        }
        if (p1) {
            a0 += bf2f(u1.x); a1 += bf2f(u1.y); a2 += bf2f(u1.z); a3 += bf2f(u1.w);
        }
    }
    if (q == 0) {  // self-loop row
        ushort4 u = ((const ushort4*)(g2b + (size_t)node * 32))[fl];
        a0 += bf2f(u.x); a1 += bf2f(u.y); a2 += bf2f(u.z); a3 += bf2f(u.w);
    }
    a0 += __shfl_xor(a0, 8);  a1 += __shfl_xor(a1, 8);
    a2 += __shfl_xor(a2, 8);  a3 += __shfl_xor(a3, 8);
    a0 += __shfl_xor(a0, 16); a1 += __shfl_xor(a1, 16);
    a2 += __shfl_xor(a2, 16); a3 += __shfl_xor(a3, 16);
    a0 += __shfl_xor(a0, 32); a1 += __shfl_xor(a1, 32);
    a2 += __shfl_xor(a2, 32); a3 += __shfl_xor(a3, 32);
    if (q == 0) {
        float di = dinv[node];
        int f0 = fl * 4;
        float4 o;
        o.x = di * a0 + b2[f0 + 0];
        o.y = di * a1 + b2[f0 + 1];
        o.z = di * a2 + b2[f0 + 2];
        o.w = di * a3 + b2[f0 + 3];
        ((float4*)(out + (size_t)node * 32))[fl] = o;
    }
}

extern "C" void kernel_launch(void* const* d_in, const int* in_sizes, int n_in,
                              void* d_out, int out_size, void* d_ws, size_t ws_size,
                              hipStream_t stream) {
    const float* x  = (const float*)d_in[0];
    const void*  ei = d_in[1];
    const float* W1 = (const float*)d_in[2];
    const float* b1 = (const float*)d_in[3];
    const float* W2 = (const float*)d_in[4];
    const float* b2 = (const float*)d_in[5];
    float* out = (float*)d_out;

    const int n_nodes = in_sizes[0] / 64;
    const int E = in_sizes[1] / 2;
    const int nb = (n_nodes + NPB - 1) / NPB;  // 196 (<= 256)

    char* p = (char*)d_ws;
    auto carve = [&](size_t bytes) {
        char* r = p;
        p += (bytes + 255) / 256 * 256;
        return r;
    };
    int* flag        = (int*)carve(sizeof(int));
    int* cnt         = (int*)carve((size_t)n_nodes * sizeof(int));
    int* rowptr      = (int*)carve(((size_t)n_nodes + 1) * sizeof(int));
    float* dinv      = (float*)carve((size_t)n_nodes * sizeof(float));
    int* bucket_wp   = (int*)carve(256 * sizeof(int));
    int* bcount      = (int*)carve(256 * sizeof(int));
    int* bucket_base = (int*)carve(256 * sizeof(int));
    int* csr         = (int*)carve((size_t)E * sizeof(int));
    unsigned int* gstage = (unsigned int*)carve((size_t)nb * BCAP * sizeof(unsigned int));
    unsigned short* g1b  = (unsigned short*)carve((size_t)n_nodes * 64 * sizeof(unsigned short));
    unsigned short* g2b  = (unsigned short*)carve((size_t)n_nodes * 32 * sizeof(unsigned short));

    k_detect<<<1, TPB, 0, stream>>>((const unsigned int*)ei, in_sizes[1], flag, bucket_wp);
    k_binA<<<(E + TILE_E - 1) / TILE_E, TPB, 0, stream>>>(ei, flag, E, nb, gstage, bucket_wp);
    k_bscan<<<1, TPB, 0, stream>>>(bucket_wp, nb, bcount, bucket_base, rowptr, n_nodes);
    k_csrB<<<nb, 512, 0, stream>>>(gstage, bcount, bucket_base, csr, cnt, rowptr, n_nodes);
    k_gemm1<<<(n_nodes + 15) / 16, TPB, 0, stream>>>(x, W1, cnt, dinv, g1b, n_nodes);
    k_pull1f<<<(n_nodes + 3) / 4, TPB, 0, stream>>>(rowptr, csr, g1b, dinv, b1, W2, g2b, n_nodes);
    k_pull2<<<(n_nodes + 3) / 4, TPB, 0, stream>>>(rowptr, csr, g2b, dinv, b2, out, n_nodes);
}

// Round 6
// 177.036 us; speedup vs baseline: 1.0835x; 1.0835x over previous
//
#include <hip/hip_runtime.h>

// 2-layer GCN, pull-based aggregation, bf16 gather tables.
// Gathers: 16 lanes/row (ushort4) => 4 rows per wave-load; indices prefetched
// wave-wide and shfl-broadcast; 4 loads in flight (manual unroll).

#define TPB 256
#define NPB 512     // nodes per bucket (dst >> 9)
#define BCAP 8192   // max edges per bucket (mean ~6122)
#define TILE_E 2048 // edges per binning block

__device__ __forceinline__ float bf2f(unsigned short u) {
    unsigned int v = ((unsigned int)u) << 16;
    return __builtin_bit_cast(float, v);
}
__device__ __forceinline__ unsigned short f2bf(float f) {
    unsigned int u = __builtin_bit_cast(unsigned int, f);
    u += 0x7FFFu + ((u >> 16) & 1u);  // round-to-nearest-even
    return (unsigned short)(u >> 16);
}

__device__ __forceinline__ int edge_val(const void* ei, int is64, long long idx) {
    if (is64) return (int)((const long long*)ei)[idx];
    return ((const int*)ei)[idx];
}

// int64 vs int32 edge buffer detect; also zero bucket_wp.
__global__ void k_detect(const unsigned int* __restrict__ w, int nelems, int* flag,
                         int* __restrict__ bucket_wp) {
    __shared__ unsigned int red[TPB];
    bucket_wp[threadIdx.x] = 0;
    unsigned int acc = 0;
    int limit = nelems < 16384 ? nelems : 16384;
    for (int i = 1 + 2 * (int)threadIdx.x; i < limit; i += 2 * TPB) acc |= w[i];
    red[threadIdx.x] = acc;
    __syncthreads();
    for (int s = TPB / 2; s > 0; s >>= 1) {
        if ((int)threadIdx.x < s) red[threadIdx.x] |= red[threadIdx.x + s];
        __syncthreads();
    }
    if (threadIdx.x == 0) *flag = (red[0] == 0u) ? 1 : 0;
}

// Pass A: bin edges by bucket = dst>>9 into gstage (bucket-major, BCAP stride).
__launch_bounds__(TPB)
__global__ void k_binA(const void* __restrict__ ei, const int* __restrict__ flag, int E,
                       int nb, unsigned int* __restrict__ gstage, int* __restrict__ bucket_wp) {
    __shared__ int lcnt[256];
    __shared__ int lboff[256];
    __shared__ int lrank[256];
    __shared__ int gbase[256];
    __shared__ int sh[256];
    __shared__ unsigned int spair[TILE_E];
    __shared__ unsigned char sbuck[TILE_E];
    int is64 = *flag;
    int t = threadIdx.x;
    int base_e = blockIdx.x * TILE_E;
    int ne = E - base_e;
    if (ne > TILE_E) ne = TILE_E;

    lcnt[t] = 0;
    lrank[t] = 0;
    __syncthreads();

    int myb[8];
    unsigned int mypair[8];
#pragma unroll
    for (int k = 0; k < 8; ++k) {
        int idx = t + k * TPB;
        myb[k] = -1;
        if (idx < ne) {
            long long e = base_e + idx;
            int s = edge_val(ei, is64, e);
            int d = edge_val(ei, is64, (long long)E + e);
            int b = d >> 9;
            myb[k] = b;
            mypair[k] = (unsigned int)s | ((unsigned int)(d & (NPB - 1)) << 20);
            atomicAdd(&lcnt[b], 1);
        }
    }
    __syncthreads();

    int v0 = lcnt[t];
    sh[t] = v0;
    __syncthreads();
    for (int st = 1; st < TPB; st <<= 1) {
        int u = (t >= st) ? sh[t - st] : 0;
        __syncthreads();
        sh[t] += u;
        __syncthreads();
    }
    lboff[t] = sh[t] - v0;
    if (t < nb && v0 > 0) gbase[t] = atomicAdd(&bucket_wp[t], v0);
    __syncthreads();

#pragma unroll
    for (int k = 0; k < 8; ++k) {
        int b = myb[k];
        if (b >= 0) {
            int r = atomicAdd(&lrank[b], 1);
            int slot = lboff[b] + r;
            spair[slot] = mypair[k];
            sbuck[slot] = (unsigned char)b;
        }
    }
    __syncthreads();

    for (int j = t; j < ne; j += TPB) {
        int b = sbuck[j];
        int pos = gbase[b] + (j - lboff[b]);
        if (pos < BCAP) gstage[(size_t)b * BCAP + pos] = spair[j];
    }
}

__global__ void k_bscan(const int* __restrict__ bucket_wp, int nb, int* __restrict__ bcount,
                        int* __restrict__ bucket_base, int* __restrict__ rowptr, int n_nodes) {
    __shared__ int sh[TPB];
    int t = threadIdx.x;
    int c = (t < nb) ? bucket_wp[t] : 0;
    if (c > BCAP) c = BCAP;
    sh[t] = c;
    __syncthreads();
    for (int st = 1; st < TPB; st <<= 1) {
        int u = (t >= st) ? sh[t - st] : 0;
        __syncthreads();
        sh[t] += u;
        __syncthreads();
    }
    if (t < nb) {
        bcount[t] = c;
        bucket_base[t] = sh[t] - c;
    }
    if (t == TPB - 1) rowptr[n_nodes] = sh[t];
}

// Pass B: per bucket, build CSR segment in LDS; coalesced csr/cnt/rowptr writes.
__launch_bounds__(512)
__global__ void k_csrB(const unsigned int* __restrict__ gstage, const int* __restrict__ bcount,
                       const int* __restrict__ bucket_base, int* __restrict__ csr,
                       int* __restrict__ cnt, int* __restrict__ rowptr, int n_nodes) {
    __shared__ int lcnt[NPB];
    __shared__ int lptr[NPB];
    __shared__ int lrank[NPB];
    __shared__ int sh[NPB];
    __shared__ int lsrc[BCAP];
    int b = blockIdx.x;
    int t = threadIdx.x;
    int cb = bcount[b];
    const unsigned int* gp = gstage + (size_t)b * BCAP;
    int cbase = bucket_base[b];

    lcnt[t] = 0;
    lrank[t] = 0;
    __syncthreads();
    for (int j = t; j < cb; j += 512) atomicAdd(&lcnt[gp[j] >> 20], 1);
    __syncthreads();
    int v0 = lcnt[t];
    sh[t] = v0;
    __syncthreads();
    for (int st = 1; st < NPB; st <<= 1) {
        int u = (t >= st) ? sh[t - st] : 0;
        __syncthreads();
        sh[t] += u;
        __syncthreads();
    }
    lptr[t] = sh[t] - v0;
    int node = b * NPB + t;
    if (node < n_nodes) {
        rowptr[node] = cbase + lptr[t];
        cnt[node] = v0;
    }
    __syncthreads();
    for (int j = t; j < cb; j += 512) {
        unsigned int w = gp[j];
        int dl = w >> 20;
        int r = atomicAdd(&lrank[dl], 1);
        lsrc[lptr[dl] + r] = (int)(w & 0xFFFFFu);
    }
    __syncthreads();
    for (int j = t; j < cb; j += 512) csr[cbase + j] = lsrc[j];
}

// g1b[n] = bf16((x[n]@W1)*dinv[n]); dinv from cnt+1. 16 nodes/block, float4 staging.
__launch_bounds__(TPB)
__global__ void k_gemm1(const float* __restrict__ x, const float* __restrict__ W1,
                        const int* __restrict__ cnt, float* __restrict__ dinv,
                        unsigned short* __restrict__ g1b, int n_nodes) {
    __shared__ float Ws[64][64];
    __shared__ float Xs[16][64];
    int t = threadIdx.x;
    for (int i = t; i < 1024; i += TPB) ((float4*)Ws)[i] = ((const float4*)W1)[i];
    int node0 = blockIdx.x * 16;
    {
        int nl = t >> 4, c = t & 15;
        int node = node0 + nl;
        float4 v = make_float4(0.f, 0.f, 0.f, 0.f);
        if (node < n_nodes) v = ((const float4*)(x + (size_t)node * 64))[c];
        ((float4*)Xs[nl])[c] = v;
    }
    __syncthreads();
    int f = t & 63;
#pragma unroll
    for (int it = 0; it < 4; ++it) {
        int nl = (t >> 6) + 4 * it;
        int node = node0 + nl;
        if (node >= n_nodes) continue;
        float acc = 0.f;
#pragma unroll
        for (int k = 0; k < 64; ++k) acc += Xs[nl][k] * Ws[k][f];
        float di = rsqrtf((float)(cnt[node] + 1));
        g1b[(size_t)node * 64 + f] = f2bf(acc * di);
        if (f == 0) dinv[node] = di;
    }
}

// Fused layer1 pull + layer2 GEMM. 1 wave/node, 4 nodes/block.
// q = lane>>4 (edge slot 0..3), fl = lane&15 (4 feats). Indices prefetched
// wave-wide; 4 independent gathers in flight per iteration (16 edges).
__launch_bounds__(TPB)
__global__ void k_pull1f(const int* __restrict__ rowptr, const int* __restrict__ csr,
                         const unsigned short* __restrict__ g1b, const float* __restrict__ dinv,
                         const float* __restrict__ b1, const float* __restrict__ W2,
                         unsigned short* __restrict__ g2b, int n_nodes) {
    __shared__ float Ws[64][32];
    __shared__ float Hs[4][64];
    __shared__ float dins[4];
    int t = threadIdx.x;
    for (int i = t; i < 64 * 32; i += TPB) Ws[i >> 5][i & 31] = W2[i];
    int node0 = blockIdx.x * 4;
    int w = t >> 6, lane = t & 63;
    int q = lane >> 4, fl = lane & 15;
    int node = node0 + w;
    if (node < n_nodes) {
        int base = rowptr[node], cntv = rowptr[node + 1] - base;
        float a0 = 0.f, a1 = 0.f, a2 = 0.f, a3 = 0.f;
        for (int off = 0; off < cntv; off += 64) {
            int rem = cntv - off;
            if (rem > 64) rem = 64;
            int idx = (lane < rem) ? csr[base + off + lane] : 0;
            for (int g = 0; g < rem; g += 16) {
                int e0 = g + q, e1 = g + 4 + q, e2 = g + 8 + q, e3 = g + 12 + q;
                int s0 = __shfl(idx, e0), s1 = __shfl(idx, e1);
                int s2 = __shfl(idx, e2), s3 = __shfl(idx, e3);
                // unconditional loads (row 0 dummies are L2-hot), predicated adds
                ushort4 u0 = ((const ushort4*)(g1b + (size_t)s0 * 64))[fl];
                ushort4 u1 = ((const ushort4*)(g1b + (size_t)s1 * 64))[fl];
                ushort4 u2 = ((const ushort4*)(g1b + (size_t)s2 * 64))[fl];
                ushort4 u3 = ((const ushort4*)(g1b + (size_t)s3 * 64))[fl];
                if (e0 < rem) {
                    a0 += bf2f(u0.x); a1 += bf2f(u0.y); a2 += bf2f(u0.z); a3 += bf2f(u0.w);
                }
                if (e1 < rem) {
                    a0 += bf2f(u1.x); a1 += bf2f(u1.y); a2 += bf2f(u1.z); a3 += bf2f(u1.w);
                }
                if (e2 < rem) {
                    a0 += bf2f(u2.x); a1 += bf2f(u2.y); a2 += bf2f(u2.z); a3 += bf2f(u2.w);
                }
                if (e3 < rem) {
                    a0 += bf2f(u3.x); a1 += bf2f(u3.y); a2 += bf2f(u3.z); a3 += bf2f(u3.w);
                }
            }
        }
        if (q == 0) {  // self-loop row
            ushort4 u = ((const ushort4*)(g1b + (size_t)node * 64))[fl];
            a0 += bf2f(u.x); a1 += bf2f(u.y); a2 += bf2f(u.z); a3 += bf2f(u.w);
        }
        // reduce over edge slots (lane bits 4,5)
        a0 += __shfl_xor(a0, 16); a1 += __shfl_xor(a1, 16);
        a2 += __shfl_xor(a2, 16); a3 += __shfl_xor(a3, 16);
        a0 += __shfl_xor(a0, 32); a1 += __shfl_xor(a1, 32);
        a2 += __shfl_xor(a2, 32); a3 += __shfl_xor(a3, 32);
        if (q == 0) {
            float di = dinv[node];
            int f0 = fl * 4;
            float4 h;
            h.x = di * a0 + b1[f0 + 0];
            h.y = di * a1 + b1[f0 + 1];
            h.z = di * a2 + b1[f0 + 2];
            h.w = di * a3 + b1[f0 + 3];
            ((float4*)Hs[w])[fl] = h;
            if (fl == 0) dins[w] = di;
        }
    } else if (lane < 16) {
        ((float4*)Hs[w])[lane] = make_float4(0.f, 0.f, 0.f, 0.f);
    }
    __syncthreads();
    if (t < 128) {
        int nl = t >> 5, f = t & 31;
        int n2 = node0 + nl;
        if (n2 < n_nodes) {
            float acc = 0.f;
#pragma unroll
            for (int k = 0; k < 64; ++k) acc += Hs[nl][k] * Ws[k][f];
            g2b[(size_t)n2 * 32 + f] = f2bf(acc * dins[nl]);
        }
    }
}

// Layer2 pull. 1 wave/node. q = lane>>3 (slot 0..7), fl = lane&7 (4 feats).
// 2 independent gathers in flight (16 edges/iter).
__global__ void k_pull2(const int* __restrict__ rowptr, const int* __restrict__ csr,
                        const unsigned short* __restrict__ g2b, const float* __restrict__ dinv,
                        const float* __restrict__ b2, float* __restrict__ out, int n_nodes) {
    int node = blockIdx.x * 4 + (threadIdx.x >> 6);
    int lane = threadIdx.x & 63;
    int q = lane >> 3, fl = lane & 7;
    if (node >= n_nodes) return;
    int base = rowptr[node], cntv = rowptr[node + 1] - base;
    float a0 = 0.f, a1 = 0.f, a2 = 0.f, a3 = 0.f;
    for (int off = 0; off < cntv; off += 64) {
        int rem = cntv - off;
        if (rem > 64) rem = 64;
        int idx = (lane < rem) ? csr[base + off + lane] : 0;
        for (int g = 0; g < rem; g += 16) {
            int e0 = g + q, e1 = g + 8 + q;
            int s0 = __shfl(idx, e0), s1 = __shfl(idx, e1);
            ushort4 u0 = ((const ushort4*)(g2b + (size_t)s0 * 32))[fl];
            ushort4 u1 = ((const ushort4*)(g2b + (size_t)s1 * 32))[fl];
            if (e0 < rem) {
                a0 += bf2f(u0.x); a1 += bf2f(u0.y); a2 += bf2f(u0.z); a3 += bf2f(u0.w);
            }
            if (e1 < rem) {
                a0 += bf2f(u1.x); a1 += bf2f(u1.y); a2 += bf2f(u1.z); a3 += bf2f(u1.w);
            }
        }
    }
    if (q == 0) {  // self-loop row
        ushort4 u = ((const ushort4*)(g2b + (size_t)node * 32))[fl];
        a0 += bf2f(u.x); a1 += bf2f(u.y); a2 += bf2f(u.z); a3 += bf2f(u.w);
    }
    a0 += __shfl_xor(a0, 8);  a1 += __shfl_xor(a1, 8);
    a2 += __shfl_xor(a2, 8);  a3 += __shfl_xor(a3, 8);
    a0 += __shfl_xor(a0, 16); a1 += __shfl_xor(a1, 16);
    a2 += __shfl_xor(a2, 16); a3 += __shfl_xor(a3, 16);
    a0 += __shfl_xor(a0, 32); a1 += __shfl_xor(a1, 32);
    a2 += __shfl_xor(a2, 32); a3 += __shfl_xor(a3, 32);
    if (q == 0) {
        float di = dinv[node];
        int f0 = fl * 4;
        float4 o;
        o.x = di * a0 + b2[f0 + 0];
        o.y = di * a1 + b2[f0 + 1];
        o.z = di * a2 + b2[f0 + 2];
        o.w = di * a3 + b2[f0 + 3];
        ((float4*)(out + (size_t)node * 32))[fl] = o;
    }
}

extern "C" void kernel_launch(void* const* d_in, const int* in_sizes, int n_in,
                              void* d_out, int out_size, void* d_ws, size_t ws_size,
                              hipStream_t stream) {
    const float* x  = (const float*)d_in[0];
    const void*  ei = d_in[1];
    const float* W1 = (const float*)d_in[2];
    const float* b1 = (const float*)d_in[3];
    const float* W2 = (const float*)d_in[4];
    const float* b2 = (const float*)d_in[5];
    float* out = (float*)d_out;

    const int n_nodes = in_sizes[0] / 64;
    const int E = in_sizes[1] / 2;
    const int nb = (n_nodes + NPB - 1) / NPB;  // 196 (<= 256)

    char* p = (char*)d_ws;
    auto carve = [&](size_t bytes) {
        char* r = p;
        p += (bytes + 255) / 256 * 256;
        return r;
    };
    int* flag        = (int*)carve(sizeof(int));
    int* cnt         = (int*)carve((size_t)n_nodes * sizeof(int));
    int* rowptr      = (int*)carve(((size_t)n_nodes + 1) * sizeof(int));
    float* dinv      = (float*)carve((size_t)n_nodes * sizeof(float));
    int* bucket_wp   = (int*)carve(256 * sizeof(int));
    int* bcount      = (int*)carve(256 * sizeof(int));
    int* bucket_base = (int*)carve(256 * sizeof(int));
    int* csr         = (int*)carve((size_t)E * sizeof(int));
    unsigned int* gstage = (unsigned int*)carve((size_t)nb * BCAP * sizeof(unsigned int));
    unsigned short* g1b  = (unsigned short*)carve((size_t)n_nodes * 64 * sizeof(unsigned short));
    unsigned short* g2b  = (unsigned short*)carve((size_t)n_nodes * 32 * sizeof(unsigned short));

    k_detect<<<1, TPB, 0, stream>>>((const unsigned int*)ei, in_sizes[1], flag, bucket_wp);
    k_binA<<<(E + TILE_E - 1) / TILE_E, TPB, 0, stream>>>(ei, flag, E, nb, gstage, bucket_wp);
    k_bscan<<<1, TPB, 0, stream>>>(bucket_wp, nb, bcount, bucket_base, rowptr, n_nodes);
    k_csrB<<<nb, 512, 0, stream>>>(gstage, bcount, bucket_base, csr, cnt, rowptr, n_nodes);
    k_gemm1<<<(n_nodes + 15) / 16, TPB, 0, stream>>>(x, W1, cnt, dinv, g1b, n_nodes);
    k_pull1f<<<(n_nodes + 3) / 4, TPB, 0, stream>>>(rowptr, csr, g1b, dinv, b1, W2, g2b, n_nodes);
    k_pull2<<<(n_nodes + 3) / 4, TPB, 0, stream>>>(rowptr, csr, g2b, dinv, b2, out, n_nodes);
}